// Round 1
// baseline (961.322 us; speedup 1.0000x reference)
//
#include <hip/hip_runtime.h>
#include <math.h>

#define NA 16384
#define ER 524288
#define EB 32768
#define ET 557056
#define INV_NORM 0.17149858514250882f   // 1/sqrt((ER+EB)/NA) = 1/sqrt(34)
#define SQRT3 1.7320508075688772f
#define RB_STEP (1.5f/9.0f)

__device__ __forceinline__ float sigmoidf_(float x) { return 1.f / (1.f + __expf(-x)); }

__device__ __forceinline__ int edge_dst(int e, const int* __restrict__ rad, const int* __restrict__ bon) {
  return (e < ER) ? rad[ER + e] : bon[EB + (e - ER)];
}

// ---------------- CSR build ----------------
__global__ void k_zero(int* __restrict__ count) {
  count[blockIdx.x * 256 + threadIdx.x] = 0;
}

__global__ void k_hist(const int* __restrict__ rad, const int* __restrict__ bon, int* __restrict__ count) {
  int e = blockIdx.x * 256 + threadIdx.x;
  atomicAdd(&count[edge_dst(e, rad, bon)], 1);
}

__global__ void k_scan(int* __restrict__ count, int* __restrict__ offsets) {
  __shared__ int part[256];
  int t = threadIdx.x;
  int base = t * 64;
  int s = 0;
  for (int j = 0; j < 64; ++j) s += count[base + j];
  part[t] = s;
  __syncthreads();
  for (int off = 1; off < 256; off <<= 1) {
    int v = (t >= off) ? part[t - off] : 0;
    __syncthreads();
    part[t] += v;
    __syncthreads();
  }
  int run = part[t] - s;  // exclusive prefix
  for (int j = 0; j < 64; ++j) {
    int c = count[base + j];
    offsets[base + j] = run;
    count[base + j] = run;  // becomes cursor for k_fill
    run += c;
  }
  if (t == 255) offsets[NA] = run;
}

__global__ void k_fill(const int* __restrict__ rad, const int* __restrict__ bon,
                       int* __restrict__ cursor, int* __restrict__ sorted) {
  int e = blockIdx.x * 256 + threadIdx.x;
  int d = edge_dst(e, rad, bon);
  int slot = atomicAdd(&cursor[d], 1);
  sorted[slot] = e;
}

// ---------------- embedding ----------------
__global__ void k_embed(const float* __restrict__ atom_tab, const int* __restrict__ types,
                        const float* __restrict__ ns0_w, const float* __restrict__ cnoise,
                        float* __restrict__ s_feat) {
  int tid = blockIdx.x * 256 + threadIdx.x;
  int n = tid >> 6, c = tid & 63;
  float cn = cnoise[0];
  s_feat[tid] = atom_tab[types[n] * 64 + c] * (1.f + cn * ns0_w[c]);
}

// ---------------- initial aggregation (wave per node, lane = channel) ----------------
__global__ __launch_bounds__(256) void k_agg0(
    const float* __restrict__ pos, const float* __restrict__ bond_tab,
    const float* __restrict__ We0, const float* __restrict__ We1,
    const int* __restrict__ rad, const int* __restrict__ bon,
    const int* __restrict__ offsets, const int* __restrict__ sorted,
    const float* __restrict__ s_feat,
    float* __restrict__ a_s, float* __restrict__ a_v) {
  int lane = threadIdx.x & 63;
  int n = blockIdx.x * 4 + (threadIdx.x >> 6);
  int c = lane;
  // radial-half weight columns in registers; bond-half folded into 2 scalars each
  float w0r[8], w1r[8];
  float w0b0 = 0, w0b1 = 0, w1b0 = 0, w1b1 = 0;
#pragma unroll
  for (int k = 0; k < 8; ++k) {
    w0r[k] = We0[(8 + k) * 64 + c];
    w1r[k] = We1[(8 + k) * 64 + c];
    float bt0 = bond_tab[k], bt1 = bond_tab[8 + k];
    float c0 = We0[k * 64 + c], c1 = We1[k * 64 + c];
    w0b0 += bt0 * c0; w0b1 += bt1 * c0;
    w1b0 += bt0 * c1; w1b1 += bt1 * c1;
  }
  float px = pos[n * 3], py = pos[n * 3 + 1], pz = pos[n * 3 + 2];
  float acc = 0, a0 = 0, a1 = 0, a2 = 0;
  int beg = offsets[n], end = offsets[n + 1];
  for (int idx = beg; idx < end; ++idx) {
    int e = sorted[idx];
    int src = (e < ER) ? rad[e] : bon[e - ER];
    float dx = pos[src * 3] - px, dy = pos[src * 3 + 1] - py, dz = pos[src * 3 + 2] - pz;
    float dist = sqrtf(dx * dx + dy * dy + dz * dz + 1e-12f);
    float inv = 1.f / dist;
    float y0 = SQRT3 * dx * inv, y1 = SQRT3 * dy * inv, y2 = SQRT3 * dz * inv;
    bool isRad = (e < ER);
    float w0 = isRad ? w0b0 : w0b1;
    float w1 = isRad ? w1b0 : w1b1;
#pragma unroll
    for (int k = 0; k < 8; ++k) {
      float diff = (dist - (k + 1) * RB_STEP) * (1.f / RB_STEP);
      float rb = 1.12f * __expf(-diff * diff);
      w0 += rb * w0r[k];
      w1 += rb * w1r[k];
    }
    float sv = s_feat[src * 64 + c];
    acc += w0 * sv;
    float t = w1 * sv;
    a0 += t * y0; a1 += t * y1; a2 += t * y2;
  }
  a_s[n * 64 + c] = acc * INV_NORM;
  float* avp = a_v + (size_t)n * 192 + c * 3;
  avp[0] = a0 * INV_NORM; avp[1] = a1 * INV_NORM; avp[2] = a2 * INV_NORM;
}

// ---------------- initial projections ----------------
__global__ void k_init_sh(const float* __restrict__ a_s, const float* __restrict__ s_feat,
                          const float* __restrict__ Ws0, const float* __restrict__ Wself0,
                          float* __restrict__ sh) {
  int tid = blockIdx.x * 256 + threadIdx.x;
  int n = tid >> 6, d = tid & 63;
  float acc = 0;
  const float* as = a_s + n * 64;
  const float* sp = s_feat + n * 64;
  for (int c = 0; c < 64; ++c)
    acc += as[c] * Ws0[c * 64 + d] + sp[c] * Wself0[c * 64 + d];
  sh[tid] = acc;
}

__global__ void k_init_vh(const float* __restrict__ a_v, const float* __restrict__ Wv0,
                          float* __restrict__ vh) {
  int tid = blockIdx.x * 256 + threadIdx.x;
  int n = tid >> 5, d = tid & 31;
  float a0 = 0, a1 = 0, a2 = 0;
  const float* av = a_v + (size_t)n * 192;
  for (int c = 0; c < 64; ++c) {
    float w = Wv0[c * 32 + d];
    a0 += av[c * 3] * w; a1 += av[c * 3 + 1] * w; a2 += av[c * 3 + 2] * w;
  }
  float* o = vh + n * 96 + d * 3;
  o[0] = a0; o[1] = a1; o[2] = a2;
}

// ---------------- layer aggregation (wave per node) ----------------
// all lanes: scalar channel c (w_ss, w_sv paths)
// lanes 0-31: vector channel vc (vdot/w_vs, w_vv); lanes 32-63: vector channel vc (w_vx cross)
__global__ __launch_bounds__(256) void k_agg_layer(
    const float* __restrict__ pos, const float* __restrict__ cnoise,
    const float* __restrict__ bond_tab,
    const float* __restrict__ Wss, const float* __restrict__ Wvs,
    const float* __restrict__ Wsv, const float* __restrict__ Wvv,
    const float* __restrict__ Wvx, const float* __restrict__ nsw,
    const int* __restrict__ rad, const int* __restrict__ bon,
    const int* __restrict__ offsets, const int* __restrict__ sorted,
    const float* __restrict__ sh_in, const float* __restrict__ vh_in,
    float* __restrict__ a_s, float* __restrict__ a_v) {
  int lane = threadIdx.x & 63;
  int n = blockIdx.x * 4 + (threadIdx.x >> 6);
  int c = lane;
  int vc = lane & 31;
  bool low = lane < 32;
  float cn = cnoise[0];

  float rss[8], rsv[8], rva[8], rvb[8];
  float bss0 = 0, bss1 = 0, bsv0 = 0, bsv1 = 0, bva0 = 0, bva1 = 0, bvb0 = 0, bvb1 = 0;
#pragma unroll
  for (int k = 0; k < 8; ++k) {
    float wss_lo = Wss[k * 64 + c], wss_hi = Wss[(8 + k) * 64 + c];
    float wsv_lo = Wsv[k * 64 + c], wsv_hi = Wsv[(8 + k) * 64 + c];
    float wa_lo = low ? Wvs[k * 32 + vc] : Wvx[k * 32 + vc];
    float wa_hi = low ? Wvs[(8 + k) * 32 + vc] : Wvx[(8 + k) * 32 + vc];
    float wb_lo = low ? Wvv[k * 32 + vc] : 0.f;
    float wb_hi = low ? Wvv[(8 + k) * 32 + vc] : 0.f;
    float bt0 = bond_tab[k], bt1 = bond_tab[8 + k];
    rss[k] = wss_hi; rsv[k] = wsv_hi; rva[k] = wa_hi; rvb[k] = wb_hi;
    bss0 += bt0 * wss_lo; bss1 += bt1 * wss_lo;
    bsv0 += bt0 * wsv_lo; bsv1 += bt1 * wsv_lo;
    bva0 += bt0 * wa_lo;  bva1 += bt1 * wa_lo;
    bvb0 += bt0 * wb_lo;  bvb1 += bt1 * wb_lo;
  }
  float scale_s = 1.f + cn * nsw[c];
  float scale_v = 1.f + cn * nsw[64 + vc];

  float px = pos[n * 3], py = pos[n * 3 + 1], pz = pos[n * 3 + 2];
  float ms = 0;                    // sum w_ss*ss
  float av0 = 0, av1 = 0, av2 = 0; // sum w_sv*ss*Y
  float ms2 = 0;                   // low lanes: sum w_vs*vdot
  float b0 = 0, b1 = 0, b2 = 0;    // low: w_vv*v ; high: w_vx*cross(v,Y)
  int beg = offsets[n], end = offsets[n + 1];
  for (int idx = beg; idx < end; ++idx) {
    int e = sorted[idx];
    int src = (e < ER) ? rad[e] : bon[e - ER];
    float dx = pos[src * 3] - px, dy = pos[src * 3 + 1] - py, dz = pos[src * 3 + 2] - pz;
    float dist = sqrtf(dx * dx + dy * dy + dz * dz + 1e-12f);
    float inv = 1.f / dist;
    float y0 = SQRT3 * dx * inv, y1 = SQRT3 * dy * inv, y2 = SQRT3 * dz * inv;
    bool isRad = (e < ER);
    float wS = isRad ? bss0 : bss1;
    float wSV = isRad ? bsv0 : bsv1;
    float wA = isRad ? bva0 : bva1;
    float wB = isRad ? bvb0 : bvb1;
#pragma unroll
    for (int k = 0; k < 8; ++k) {
      float diff = (dist - (k + 1) * RB_STEP) * (1.f / RB_STEP);
      float rb = 1.12f * __expf(-diff * diff);
      wS += rb * rss[k];
      wSV += rb * rsv[k];
      wA += rb * rva[k];
      wB += rb * rvb[k];
    }
    float ss_e = sh_in[src * 64 + c] * scale_s;
    const float* vp = vh_in + src * 96 + vc * 3;
    float v0 = vp[0] * scale_v, v1 = vp[1] * scale_v, v2 = vp[2] * scale_v;
    ms += wS * ss_e;
    float t = wSV * ss_e;
    av0 += t * y0; av1 += t * y1; av2 += t * y2;
    float vdot = v0 * y0 + v1 * y1 + v2 * y2;
    ms2 += wA * vdot;  // garbage on high lanes, never written
    float cx = v1 * y2 - v2 * y1;
    float cy = v2 * y0 - v0 * y2;
    float cz = v0 * y1 - v1 * y0;
    float m0 = low ? v0 : cx;
    float m1 = low ? v1 : cy;
    float m2 = low ? v2 : cz;
    float wM = low ? wB : wA;
    b0 += wM * m0; b1 += wM * m1; b2 += wM * m2;
  }
  a_s[n * 96 + c] = ms * INV_NORM;
  float* avn = a_v + (size_t)n * 384;
  avn[c * 3] = av0 * INV_NORM; avn[c * 3 + 1] = av1 * INV_NORM; avn[c * 3 + 2] = av2 * INV_NORM;
  if (low) {
    a_s[n * 96 + 64 + vc] = ms2 * INV_NORM;
    avn[(64 + vc) * 3] = b0 * INV_NORM;
    avn[(64 + vc) * 3 + 1] = b1 * INV_NORM;
    avn[(64 + vc) * 3 + 2] = b2 * INV_NORM;
  } else {
    avn[(96 + vc) * 3] = b0 * INV_NORM;
    avn[(96 + vc) * 3 + 1] = b1 * INV_NORM;
    avn[(96 + vc) * 3 + 2] = b2 * INV_NORM;
  }
}

// ---------------- mixing / self / skip ----------------
__global__ void k_mix_s(const float* __restrict__ a_s, const float* __restrict__ sh_in,
                        const float* __restrict__ Wmix, const float* __restrict__ Wself,
                        const float* __restrict__ nsw, const float* __restrict__ skw,
                        const float* __restrict__ skb, const float* __restrict__ cnoise,
                        float* __restrict__ sh_out) {
  int tid = blockIdx.x * 256 + threadIdx.x;
  int n = tid >> 6, d = tid & 63;
  float cn = cnoise[0];
  float acc = 0;
  const float* as = a_s + n * 96;
  for (int cc = 0; cc < 96; ++cc) acc += as[cc] * Wmix[cc * 64 + d];
  const float* sp = sh_in + n * 64;
  for (int cc = 0; cc < 64; ++cc) acc += sp[cc] * (1.f + cn * nsw[cc]) * Wself[cc * 64 + d];
  float g1 = sigmoidf_(skb[d] + cn * skw[d]);
  float g2 = sigmoidf_(skb[64 + d] + cn * skw[64 + d]);
  sh_out[tid] = g1 * sh_in[tid] + g2 * acc;
}

__global__ void k_mix_v(const float* __restrict__ a_v, const float* __restrict__ vh_in,
                        const float* __restrict__ Wmix, const float* __restrict__ Wself,
                        const float* __restrict__ nsw, const float* __restrict__ skw,
                        const float* __restrict__ skb, const float* __restrict__ cnoise,
                        float* __restrict__ vh_out) {
  int tid = blockIdx.x * 256 + threadIdx.x;
  int n = tid >> 5, d = tid & 31;
  float cn = cnoise[0];
  float a0 = 0, a1 = 0, a2 = 0;
  const float* av = a_v + (size_t)n * 384;
  for (int cc = 0; cc < 128; ++cc) {
    float w = Wmix[cc * 32 + d];
    a0 += av[cc * 3] * w; a1 += av[cc * 3 + 1] * w; a2 += av[cc * 3 + 2] * w;
  }
  const float* vp = vh_in + n * 96;
  for (int cc = 0; cc < 32; ++cc) {
    float w = Wself[cc * 32 + d] * (1.f + cn * nsw[64 + cc]);
    a0 += vp[cc * 3] * w; a1 += vp[cc * 3 + 1] * w; a2 += vp[cc * 3 + 2] * w;
  }
  float g3 = sigmoidf_(skb[128 + d] + cn * skw[128 + d]);
  float g4 = sigmoidf_(skb[160 + d] + cn * skw[160 + d]);
  float* o = vh_out + n * 96 + d * 3;
  const float* vi = vh_in + n * 96 + d * 3;
  o[0] = g3 * vi[0] + g4 * a0;
  o[1] = g3 * vi[1] + g4 * a1;
  o[2] = g3 * vi[2] + g4 * a2;
}

// ---------------- output ----------------
__global__ void k_out(const float* __restrict__ vh, const float* __restrict__ w_out,
                      const float* __restrict__ gain, float* __restrict__ out) {
  int tid = blockIdx.x * 256 + threadIdx.x;  // < NA*3
  int n = tid / 3, i = tid - n * 3;
  float acc = 0;
  for (int c = 0; c < 32; ++c) acc += vh[n * 96 + c * 3 + i] * w_out[c];
  out[tid] = acc * gain[0];
}

extern "C" void kernel_launch(void* const* d_in, const int* in_sizes, int n_in,
                              void* d_out, int out_size, void* d_ws, size_t ws_size,
                              hipStream_t stream) {
  (void)in_sizes; (void)n_in; (void)out_size; (void)ws_size;
  const float* pos     = (const float*)d_in[0];
  const float* cn      = (const float*)d_in[1];
  const int*   types   = (const int*)d_in[2];
  const int*   rad     = (const int*)d_in[3];
  const int*   bon     = (const int*)d_in[4];
  const float* atom_tab= (const float*)d_in[5];
  const float* bond_tab= (const float*)d_in[6];
  const float* ns0_w   = (const float*)d_in[7];
  const float* We0     = (const float*)d_in[8];
  const float* We1     = (const float*)d_in[9];
  const float* Wself0  = (const float*)d_in[10];
  const float* Ws0     = (const float*)d_in[11];
  const float* Wv0     = (const float*)d_in[12];
  const float* ns_w    = (const float*)d_in[13];
  const float* We_ss   = (const float*)d_in[14];
  const float* We_vs   = (const float*)d_in[15];
  const float* We_sv   = (const float*)d_in[16];
  const float* We_vv   = (const float*)d_in[17];
  const float* We_vx   = (const float*)d_in[18];
  const float* Wmix_s  = (const float*)d_in[19];
  const float* Wmix_v  = (const float*)d_in[20];
  const float* Wself_s = (const float*)d_in[21];
  const float* Wself_v = (const float*)d_in[22];
  const float* skip_w  = (const float*)d_in[23];
  const float* skip_b  = (const float*)d_in[24];
  const float* w_out   = (const float*)d_in[25];
  const float* gain    = (const float*)d_in[26];

  char* ws = (char*)d_ws;
  size_t o = 0;
  auto alloc = [&](size_t bytes) -> void* {
    void* p = ws + o;
    o += (bytes + 255) & ~(size_t)255;
    return p;
  };
  float* s_feat = (float*)alloc((size_t)NA * 64 * 4);
  float* a_s    = (float*)alloc((size_t)NA * 96 * 4);
  float* a_v    = (float*)alloc((size_t)NA * 384 * 4);
  float* sh0    = (float*)alloc((size_t)NA * 64 * 4);
  float* sh1    = (float*)alloc((size_t)NA * 64 * 4);
  float* vh0    = (float*)alloc((size_t)NA * 96 * 4);
  float* vh1    = (float*)alloc((size_t)NA * 96 * 4);
  int* count    = (int*)alloc((size_t)NA * 4);
  int* offsets  = (int*)alloc((size_t)(NA + 1) * 4);
  int* sorted   = (int*)alloc((size_t)ET * 4);
  float* shb[2] = {sh0, sh1};
  float* vhb[2] = {vh0, vh1};

  // CSR build (rebuilt every call; ws is re-poisoned by harness)
  k_zero<<<NA / 256, 256, 0, stream>>>(count);
  k_hist<<<ET / 256, 256, 0, stream>>>(rad, bon, count);
  k_scan<<<1, 256, 0, stream>>>(count, offsets);
  k_fill<<<ET / 256, 256, 0, stream>>>(rad, bon, count, sorted);

  k_embed<<<NA * 64 / 256, 256, 0, stream>>>(atom_tab, types, ns0_w, cn, s_feat);
  k_agg0<<<NA / 4, 256, 0, stream>>>(pos, bond_tab, We0, We1, rad, bon, offsets, sorted,
                                     s_feat, a_s, a_v);
  k_init_sh<<<NA * 64 / 256, 256, 0, stream>>>(a_s, s_feat, Ws0, Wself0, shb[0]);
  k_init_vh<<<NA * 32 / 256, 256, 0, stream>>>(a_v, Wv0, vhb[0]);

  for (int l = 0; l < 2; ++l) {
    int bin = l & 1, bout = 1 - bin;
    k_agg_layer<<<NA / 4, 256, 0, stream>>>(
        pos, cn, bond_tab,
        We_ss + l * 16 * 64, We_vs + l * 16 * 32, We_sv + l * 16 * 64,
        We_vv + l * 16 * 32, We_vx + l * 16 * 32, ns_w + l * 96,
        rad, bon, offsets, sorted, shb[bin], vhb[bin], a_s, a_v);
    k_mix_s<<<NA * 64 / 256, 256, 0, stream>>>(
        a_s, shb[bin], Wmix_s + l * 96 * 64, Wself_s + l * 64 * 64,
        ns_w + l * 96, skip_w + l * 192, skip_b + l * 192, cn, shb[bout]);
    k_mix_v<<<NA * 32 / 256, 256, 0, stream>>>(
        a_v, vhb[bin], Wmix_v + l * 128 * 32, Wself_v + l * 32 * 32,
        ns_w + l * 96, skip_w + l * 192, skip_b + l * 192, cn, vhb[bout]);
  }
  k_out<<<NA * 3 / 256, 256, 0, stream>>>(vhb[0], w_out, gain, (float*)d_out);
}

// Round 2
// 666.378 us; speedup vs baseline: 1.4426x; 1.4426x over previous
//
#include <hip/hip_runtime.h>
#include <math.h>

#define NA 16384
#define ER 524288
#define EB 32768
#define ET 557056
#define INV_NORM 0.17149858514250882f   // 1/sqrt((ER+EB)/NA) = 1/sqrt(34)
#define SQRT3 1.7320508075688772f
#define RB_STEP (1.5f/9.0f)

__device__ __forceinline__ float sigmoidf_(float x) { return 1.f / (1.f + __expf(-x)); }

__device__ __forceinline__ int edge_dst(int e, const int* __restrict__ rad, const int* __restrict__ bon) {
  return (e < ER) ? rad[ER + e] : bon[EB + (e - ER)];
}

// ---------------- CSR build ----------------
__global__ void k_zero(int* __restrict__ count) {
  count[blockIdx.x * 256 + threadIdx.x] = 0;
}

__global__ void k_hist(const int* __restrict__ rad, const int* __restrict__ bon, int* __restrict__ count) {
  int e = blockIdx.x * 256 + threadIdx.x;
  atomicAdd(&count[edge_dst(e, rad, bon)], 1);
}

__global__ void k_scan(int* __restrict__ count, int* __restrict__ offsets) {
  __shared__ int part[256];
  int t = threadIdx.x;
  int base = t * 64;
  int s = 0;
  for (int j = 0; j < 64; ++j) s += count[base + j];
  part[t] = s;
  __syncthreads();
  for (int off = 1; off < 256; off <<= 1) {
    int v = (t >= off) ? part[t - off] : 0;
    __syncthreads();
    part[t] += v;
    __syncthreads();
  }
  int run = part[t] - s;  // exclusive prefix
  for (int j = 0; j < 64; ++j) {
    int c = count[base + j];
    offsets[base + j] = run;
    count[base + j] = run;  // becomes cursor for k_fill
    run += c;
  }
  if (t == 255) offsets[NA] = run;
}

__global__ void k_fill(const int* __restrict__ rad, const int* __restrict__ bon,
                       int* __restrict__ cursor, int* __restrict__ sorted) {
  int e = blockIdx.x * 256 + threadIdx.x;
  int d = edge_dst(e, rad, bon);
  int slot = atomicAdd(&cursor[d], 1);
  sorted[slot] = e;
}

// ---------------- per-edge record precompute ----------------
// record[idx] (48B, CSR slot order): {src|(isBond<<16), Y0,Y1,Y2}, {rb0..3}, {rb4..7}
__global__ void k_edge_pre(const float* __restrict__ pos,
                           const int* __restrict__ rad, const int* __restrict__ bon,
                           const int* __restrict__ sorted, float4* __restrict__ rec) {
  int idx = blockIdx.x * 256 + threadIdx.x;
  int e = sorted[idx];
  int src, dst, flag;
  if (e < ER) { src = rad[e]; dst = rad[ER + e]; flag = 0; }
  else        { src = bon[e - ER]; dst = bon[EB + e - ER]; flag = 1 << 16; }
  float dx = pos[src * 3] - pos[dst * 3];
  float dy = pos[src * 3 + 1] - pos[dst * 3 + 1];
  float dz = pos[src * 3 + 2] - pos[dst * 3 + 2];
  float dist = sqrtf(dx * dx + dy * dy + dz * dz + 1e-12f);
  float inv = 1.f / dist;
  float4* rp = rec + (size_t)idx * 3;
  rp[0] = make_float4(__int_as_float(src | flag), SQRT3 * dx * inv, SQRT3 * dy * inv, SQRT3 * dz * inv);
  float rb[8];
#pragma unroll
  for (int k = 0; k < 8; ++k) {
    float diff = (dist - (k + 1) * RB_STEP) * (1.f / RB_STEP);
    rb[k] = 1.12f * __expf(-diff * diff);
  }
  rp[1] = make_float4(rb[0], rb[1], rb[2], rb[3]);
  rp[2] = make_float4(rb[4], rb[5], rb[6], rb[7]);
}

// ---------------- embedding ----------------
__global__ void k_embed(const float* __restrict__ atom_tab, const int* __restrict__ types,
                        const float* __restrict__ ns0_w, const float* __restrict__ cnoise,
                        float* __restrict__ s_feat) {
  int tid = blockIdx.x * 256 + threadIdx.x;
  int n = tid >> 6, c = tid & 63;
  float cn = cnoise[0];
  s_feat[tid] = atom_tab[types[n] * 64 + c] * (1.f + cn * ns0_w[c]);
}

// ---------------- initial aggregation (wave per node, lane = channel) ----------------
__global__ __launch_bounds__(256, 4) void k_agg0(
    const float* __restrict__ bond_tab,
    const float* __restrict__ We0, const float* __restrict__ We1,
    const int* __restrict__ offsets, const float4* __restrict__ rec,
    const float* __restrict__ s_feat,
    float* __restrict__ a_s, float* __restrict__ a_v) {
  int lane = threadIdx.x & 63;
  int n = blockIdx.x * 4 + (threadIdx.x >> 6);
  int c = lane;
  float w0r[8], w1r[8];
  float w0b0 = 0, w0b1 = 0, w1b0 = 0, w1b1 = 0;
#pragma unroll
  for (int k = 0; k < 8; ++k) {
    w0r[k] = We0[(8 + k) * 64 + c];
    w1r[k] = We1[(8 + k) * 64 + c];
    float bt0 = bond_tab[k], bt1 = bond_tab[8 + k];
    float c0 = We0[k * 64 + c], c1 = We1[k * 64 + c];
    w0b0 += bt0 * c0; w0b1 += bt1 * c0;
    w1b0 += bt0 * c1; w1b1 += bt1 * c1;
  }
  float acc = 0, a0 = 0, a1 = 0, a2 = 0;
  int beg = __builtin_amdgcn_readfirstlane(offsets[n]);
  int end = __builtin_amdgcn_readfirstlane(offsets[n + 1]);
  for (int idx = beg; idx < end; ++idx) {
    const float4* rp = rec + (size_t)idx * 3;
    float4 r0 = rp[0], r1 = rp[1], r2 = rp[2];
    int senc = __float_as_int(r0.x);
    int src = senc & 0xFFFF;
    bool isB = senc >= (1 << 16);
    float w0 = isB ? w0b1 : w0b0;
    float w1 = isB ? w1b1 : w1b0;
    w0 += r1.x * w0r[0] + r1.y * w0r[1] + r1.z * w0r[2] + r1.w * w0r[3]
        + r2.x * w0r[4] + r2.y * w0r[5] + r2.z * w0r[6] + r2.w * w0r[7];
    w1 += r1.x * w1r[0] + r1.y * w1r[1] + r1.z * w1r[2] + r1.w * w1r[3]
        + r2.x * w1r[4] + r2.y * w1r[5] + r2.z * w1r[6] + r2.w * w1r[7];
    float sv = s_feat[src * 64 + c];
    acc += w0 * sv;
    float t = w1 * sv;
    a0 += t * r0.y; a1 += t * r0.z; a2 += t * r0.w;
  }
  a_s[n * 64 + c] = acc * INV_NORM;
  float* avp = a_v + (size_t)n * 192 + c * 3;
  avp[0] = a0 * INV_NORM; avp[1] = a1 * INV_NORM; avp[2] = a2 * INV_NORM;
}

// ---------------- initial projections ----------------
__global__ void k_init_sh(const float* __restrict__ a_s, const float* __restrict__ s_feat,
                          const float* __restrict__ Ws0, const float* __restrict__ Wself0,
                          float* __restrict__ sh) {
  int tid = blockIdx.x * 256 + threadIdx.x;
  int n = tid >> 6, d = tid & 63;
  float acc = 0;
  const float* as = a_s + n * 64;
  const float* sp = s_feat + n * 64;
  for (int c = 0; c < 64; ++c)
    acc += as[c] * Ws0[c * 64 + d] + sp[c] * Wself0[c * 64 + d];
  sh[tid] = acc;
}

// vh padded layout: [n][32][4] floats (w unused)
__global__ void k_init_vh(const float* __restrict__ a_v, const float* __restrict__ Wv0,
                          float* __restrict__ vh) {
  int tid = blockIdx.x * 256 + threadIdx.x;
  int n = tid >> 5, d = tid & 31;
  float a0 = 0, a1 = 0, a2 = 0;
  const float* av = a_v + (size_t)n * 192;
  for (int c = 0; c < 64; ++c) {
    float w = Wv0[c * 32 + d];
    a0 += av[c * 3] * w; a1 += av[c * 3 + 1] * w; a2 += av[c * 3 + 2] * w;
  }
  float* o = vh + (size_t)n * 128 + d * 4;
  o[0] = a0; o[1] = a1; o[2] = a2;
}

// ---------------- layer aggregation (wave per node) ----------------
__global__ __launch_bounds__(256, 4) void k_agg_layer(
    const float* __restrict__ cnoise, const float* __restrict__ bond_tab,
    const float* __restrict__ Wss, const float* __restrict__ Wvs,
    const float* __restrict__ Wsv, const float* __restrict__ Wvv,
    const float* __restrict__ Wvx, const float* __restrict__ nsw,
    const int* __restrict__ offsets, const float4* __restrict__ rec,
    const float* __restrict__ sh_in, const float4* __restrict__ vh_in,
    float* __restrict__ a_s, float* __restrict__ a_v) {
  int lane = threadIdx.x & 63;
  int n = blockIdx.x * 4 + (threadIdx.x >> 6);
  int c = lane;
  int vc = lane & 31;
  bool low = lane < 32;
  float cn = cnoise[0];

  float rss[8], rsv[8], rva[8], rvb[8];
  float bss0 = 0, bss1 = 0, bsv0 = 0, bsv1 = 0, bva0 = 0, bva1 = 0, bvb0 = 0, bvb1 = 0;
#pragma unroll
  for (int k = 0; k < 8; ++k) {
    float wss_lo = Wss[k * 64 + c], wss_hi = Wss[(8 + k) * 64 + c];
    float wsv_lo = Wsv[k * 64 + c], wsv_hi = Wsv[(8 + k) * 64 + c];
    float wa_lo = low ? Wvs[k * 32 + vc] : Wvx[k * 32 + vc];
    float wa_hi = low ? Wvs[(8 + k) * 32 + vc] : Wvx[(8 + k) * 32 + vc];
    float wb_lo = low ? Wvv[k * 32 + vc] : 0.f;
    float wb_hi = low ? Wvv[(8 + k) * 32 + vc] : 0.f;
    float bt0 = bond_tab[k], bt1 = bond_tab[8 + k];
    rss[k] = wss_hi; rsv[k] = wsv_hi; rva[k] = wa_hi; rvb[k] = wb_hi;
    bss0 += bt0 * wss_lo; bss1 += bt1 * wss_lo;
    bsv0 += bt0 * wsv_lo; bsv1 += bt1 * wsv_lo;
    bva0 += bt0 * wa_lo;  bva1 += bt1 * wa_lo;
    bvb0 += bt0 * wb_lo;  bvb1 += bt1 * wb_lo;
  }
  float scale_s = 1.f + cn * nsw[c];
  float scale_v = 1.f + cn * nsw[64 + vc];

  float ms = 0;                    // sum w_ss*sh        (scale_s folded at store)
  float av0 = 0, av1 = 0, av2 = 0; // sum w_sv*sh*Y      (scale_s folded)
  float ms2 = 0;                   // low: sum w_vs*(v.Y) (scale_v folded)
  float b0 = 0, b1 = 0, b2 = 0;    // low: w_vv*v ; high: w_vx*cross(v,Y) (scale_v folded)
  int beg = __builtin_amdgcn_readfirstlane(offsets[n]);
  int end = __builtin_amdgcn_readfirstlane(offsets[n + 1]);
  for (int idx = beg; idx < end; ++idx) {
    const float4* rp = rec + (size_t)idx * 3;
    float4 r0 = rp[0], r1 = rp[1], r2 = rp[2];
    int senc = __float_as_int(r0.x);
    int src = senc & 0xFFFF;
    bool isB = senc >= (1 << 16);
    float y0 = r0.y, y1 = r0.z, y2 = r0.w;
    float wS  = isB ? bss1 : bss0;
    float wSV = isB ? bsv1 : bsv0;
    float wA  = isB ? bva1 : bva0;
    float wB  = isB ? bvb1 : bvb0;
    wS  += r1.x * rss[0] + r1.y * rss[1] + r1.z * rss[2] + r1.w * rss[3]
         + r2.x * rss[4] + r2.y * rss[5] + r2.z * rss[6] + r2.w * rss[7];
    wSV += r1.x * rsv[0] + r1.y * rsv[1] + r1.z * rsv[2] + r1.w * rsv[3]
         + r2.x * rsv[4] + r2.y * rsv[5] + r2.z * rsv[6] + r2.w * rsv[7];
    wA  += r1.x * rva[0] + r1.y * rva[1] + r1.z * rva[2] + r1.w * rva[3]
         + r2.x * rva[4] + r2.y * rva[5] + r2.z * rva[6] + r2.w * rva[7];
    wB  += r1.x * rvb[0] + r1.y * rvb[1] + r1.z * rvb[2] + r1.w * rvb[3]
         + r2.x * rvb[4] + r2.y * rvb[5] + r2.z * rvb[6] + r2.w * rvb[7];
    float ss = sh_in[src * 64 + c];
    float4 v4 = vh_in[src * 32 + vc];
    float v0 = v4.x, v1 = v4.y, v2 = v4.z;
    ms += wS * ss;
    float t = wSV * ss;
    av0 += t * y0; av1 += t * y1; av2 += t * y2;
    float vdot = v0 * y0 + v1 * y1 + v2 * y2;
    ms2 += wA * vdot;  // garbage on high lanes, never written
    float cx = v1 * y2 - v2 * y1;
    float cy = v2 * y0 - v0 * y2;
    float cz = v0 * y1 - v1 * y0;
    float m0 = low ? v0 : cx;
    float m1 = low ? v1 : cy;
    float m2 = low ? v2 : cz;
    float wM = low ? wB : wA;
    b0 += wM * m0; b1 += wM * m1; b2 += wM * m2;
  }
  float fs = scale_s * INV_NORM;
  float fv = scale_v * INV_NORM;
  a_s[n * 96 + c] = ms * fs;
  float* avn = a_v + (size_t)n * 384;
  avn[c * 3] = av0 * fs; avn[c * 3 + 1] = av1 * fs; avn[c * 3 + 2] = av2 * fs;
  if (low) {
    a_s[n * 96 + 64 + vc] = ms2 * fv;
    avn[(64 + vc) * 3] = b0 * fv;
    avn[(64 + vc) * 3 + 1] = b1 * fv;
    avn[(64 + vc) * 3 + 2] = b2 * fv;
  } else {
    avn[(96 + vc) * 3] = b0 * fv;
    avn[(96 + vc) * 3 + 1] = b1 * fv;
    avn[(96 + vc) * 3 + 2] = b2 * fv;
  }
}

// ---------------- mixing / self / skip ----------------
__global__ void k_mix_s(const float* __restrict__ a_s, const float* __restrict__ sh_in,
                        const float* __restrict__ Wmix, const float* __restrict__ Wself,
                        const float* __restrict__ nsw, const float* __restrict__ skw,
                        const float* __restrict__ skb, const float* __restrict__ cnoise,
                        float* __restrict__ sh_out) {
  int tid = blockIdx.x * 256 + threadIdx.x;
  int n = tid >> 6, d = tid & 63;
  float cn = cnoise[0];
  float acc = 0;
  const float* as = a_s + n * 96;
  for (int cc = 0; cc < 96; ++cc) acc += as[cc] * Wmix[cc * 64 + d];
  const float* sp = sh_in + n * 64;
  for (int cc = 0; cc < 64; ++cc) acc += sp[cc] * (1.f + cn * nsw[cc]) * Wself[cc * 64 + d];
  float g1 = sigmoidf_(skb[d] + cn * skw[d]);
  float g2 = sigmoidf_(skb[64 + d] + cn * skw[64 + d]);
  sh_out[tid] = g1 * sh_in[tid] + g2 * acc;
}

__global__ void k_mix_v(const float* __restrict__ a_v, const float* __restrict__ vh_in,
                        const float* __restrict__ Wmix, const float* __restrict__ Wself,
                        const float* __restrict__ nsw, const float* __restrict__ skw,
                        const float* __restrict__ skb, const float* __restrict__ cnoise,
                        float* __restrict__ vh_out) {
  int tid = blockIdx.x * 256 + threadIdx.x;
  int n = tid >> 5, d = tid & 31;
  float cn = cnoise[0];
  float a0 = 0, a1 = 0, a2 = 0;
  const float* av = a_v + (size_t)n * 384;
  for (int cc = 0; cc < 128; ++cc) {
    float w = Wmix[cc * 32 + d];
    a0 += av[cc * 3] * w; a1 += av[cc * 3 + 1] * w; a2 += av[cc * 3 + 2] * w;
  }
  const float* vp = vh_in + (size_t)n * 128;
  for (int cc = 0; cc < 32; ++cc) {
    float w = Wself[cc * 32 + d] * (1.f + cn * nsw[64 + cc]);
    a0 += vp[cc * 4] * w; a1 += vp[cc * 4 + 1] * w; a2 += vp[cc * 4 + 2] * w;
  }
  float g3 = sigmoidf_(skb[128 + d] + cn * skw[128 + d]);
  float g4 = sigmoidf_(skb[160 + d] + cn * skw[160 + d]);
  float* o = vh_out + (size_t)n * 128 + d * 4;
  const float* vi = vh_in + (size_t)n * 128 + d * 4;
  o[0] = g3 * vi[0] + g4 * a0;
  o[1] = g3 * vi[1] + g4 * a1;
  o[2] = g3 * vi[2] + g4 * a2;
}

// ---------------- output ----------------
__global__ void k_out(const float* __restrict__ vh, const float* __restrict__ w_out,
                      const float* __restrict__ gain, float* __restrict__ out) {
  int tid = blockIdx.x * 256 + threadIdx.x;  // < NA*3
  int n = tid / 3, i = tid - n * 3;
  float acc = 0;
  for (int c = 0; c < 32; ++c) acc += vh[(size_t)n * 128 + c * 4 + i] * w_out[c];
  out[tid] = acc * gain[0];
}

extern "C" void kernel_launch(void* const* d_in, const int* in_sizes, int n_in,
                              void* d_out, int out_size, void* d_ws, size_t ws_size,
                              hipStream_t stream) {
  (void)in_sizes; (void)n_in; (void)out_size; (void)ws_size;
  const float* pos     = (const float*)d_in[0];
  const float* cn      = (const float*)d_in[1];
  const int*   types   = (const int*)d_in[2];
  const int*   rad     = (const int*)d_in[3];
  const int*   bon     = (const int*)d_in[4];
  const float* atom_tab= (const float*)d_in[5];
  const float* bond_tab= (const float*)d_in[6];
  const float* ns0_w   = (const float*)d_in[7];
  const float* We0     = (const float*)d_in[8];
  const float* We1     = (const float*)d_in[9];
  const float* Wself0  = (const float*)d_in[10];
  const float* Ws0     = (const float*)d_in[11];
  const float* Wv0     = (const float*)d_in[12];
  const float* ns_w    = (const float*)d_in[13];
  const float* We_ss   = (const float*)d_in[14];
  const float* We_vs   = (const float*)d_in[15];
  const float* We_sv   = (const float*)d_in[16];
  const float* We_vv   = (const float*)d_in[17];
  const float* We_vx   = (const float*)d_in[18];
  const float* Wmix_s  = (const float*)d_in[19];
  const float* Wmix_v  = (const float*)d_in[20];
  const float* Wself_s = (const float*)d_in[21];
  const float* Wself_v = (const float*)d_in[22];
  const float* skip_w  = (const float*)d_in[23];
  const float* skip_b  = (const float*)d_in[24];
  const float* w_out   = (const float*)d_in[25];
  const float* gain    = (const float*)d_in[26];

  char* ws = (char*)d_ws;
  size_t o = 0;
  auto alloc = [&](size_t bytes) -> void* {
    void* p = ws + o;
    o += (bytes + 255) & ~(size_t)255;
    return p;
  };
  float* s_feat = (float*)alloc((size_t)NA * 64 * 4);
  float* a_s    = (float*)alloc((size_t)NA * 96 * 4);
  float* a_v    = (float*)alloc((size_t)NA * 384 * 4);
  float* sh0    = (float*)alloc((size_t)NA * 64 * 4);
  float* sh1    = (float*)alloc((size_t)NA * 64 * 4);
  float* vh0    = (float*)alloc((size_t)NA * 128 * 4);  // padded [n][32][4]
  float* vh1    = (float*)alloc((size_t)NA * 128 * 4);
  int* count    = (int*)alloc((size_t)NA * 4);
  int* offsets  = (int*)alloc((size_t)(NA + 1) * 4);
  int* sorted   = (int*)alloc((size_t)ET * 4);
  float4* rec   = (float4*)alloc((size_t)ET * 48);
  float* shb[2] = {sh0, sh1};
  float* vhb[2] = {vh0, vh1};

  // CSR build
  k_zero<<<NA / 256, 256, 0, stream>>>(count);
  k_hist<<<ET / 256, 256, 0, stream>>>(rad, bon, count);
  k_scan<<<1, 256, 0, stream>>>(count, offsets);
  k_fill<<<ET / 256, 256, 0, stream>>>(rad, bon, count, sorted);
  k_edge_pre<<<ET / 256, 256, 0, stream>>>(pos, rad, bon, sorted, rec);

  k_embed<<<NA * 64 / 256, 256, 0, stream>>>(atom_tab, types, ns0_w, cn, s_feat);
  k_agg0<<<NA / 4, 256, 0, stream>>>(bond_tab, We0, We1, offsets, rec, s_feat, a_s, a_v);
  k_init_sh<<<NA * 64 / 256, 256, 0, stream>>>(a_s, s_feat, Ws0, Wself0, shb[0]);
  k_init_vh<<<NA * 32 / 256, 256, 0, stream>>>(a_v, Wv0, vhb[0]);

  for (int l = 0; l < 2; ++l) {
    int bin = l & 1, bout = 1 - bin;
    k_agg_layer<<<NA / 4, 256, 0, stream>>>(
        cn, bond_tab,
        We_ss + l * 16 * 64, We_vs + l * 16 * 32, We_sv + l * 16 * 64,
        We_vv + l * 16 * 32, We_vx + l * 16 * 32, ns_w + l * 96,
        offsets, rec, shb[bin], (const float4*)vhb[bin], a_s, a_v);
    k_mix_s<<<NA * 64 / 256, 256, 0, stream>>>(
        a_s, shb[bin], Wmix_s + l * 96 * 64, Wself_s + l * 64 * 64,
        ns_w + l * 96, skip_w + l * 192, skip_b + l * 192, cn, shb[bout]);
    k_mix_v<<<NA * 32 / 256, 256, 0, stream>>>(
        a_v, vhb[bin], Wmix_v + l * 128 * 32, Wself_v + l * 32 * 32,
        ns_w + l * 96, skip_w + l * 192, skip_b + l * 192, cn, vhb[bout]);
  }
  k_out<<<NA * 3 / 256, 256, 0, stream>>>(vhb[0], w_out, gain, (float*)d_out);
}

// Round 4
// 645.388 us; speedup vs baseline: 1.4895x; 1.0325x over previous
//
#include <hip/hip_runtime.h>
#include <math.h>

#define NA 16384
#define ER 524288
#define EB 32768
#define ET 557056
#define INV_NORM 0.17149858514250882f   // 1/sqrt((ER+EB)/NA) = 1/sqrt(34)
#define SQRT3 1.7320508075688772f
#define RB_STEP (1.5f/9.0f)

// Pin a value into a VGPR: opaque asm output is not rematerializable, so the
// compiler must keep it live across the edge loop instead of re-loading.
#define KEEP(x) asm volatile("" : "+v"(x))

typedef float nfloat4 __attribute__((ext_vector_type(4)));

__device__ __forceinline__ float sigmoidf_(float x) { return 1.f / (1.f + __expf(-x)); }

__device__ __forceinline__ float4 ntl4(const float4* p) {
  nfloat4 v = __builtin_nontemporal_load((const nfloat4*)p);
  return make_float4(v.x, v.y, v.z, v.w);
}

__device__ __forceinline__ int edge_dst(int e, const int* __restrict__ rad, const int* __restrict__ bon) {
  return (e < ER) ? rad[ER + e] : bon[EB + (e - ER)];
}

// ---------------- CSR build ----------------
__global__ void k_zero(int* __restrict__ count) {
  count[blockIdx.x * 256 + threadIdx.x] = 0;
}

__global__ void k_hist(const int* __restrict__ rad, const int* __restrict__ bon, int* __restrict__ count) {
  int e = blockIdx.x * 256 + threadIdx.x;
  atomicAdd(&count[edge_dst(e, rad, bon)], 1);
}

__global__ void k_scan(int* __restrict__ count, int* __restrict__ offsets) {
  __shared__ int part[256];
  int t = threadIdx.x;
  int base = t * 64;
  int s = 0;
  for (int j = 0; j < 64; ++j) s += count[base + j];
  part[t] = s;
  __syncthreads();
  for (int off = 1; off < 256; off <<= 1) {
    int v = (t >= off) ? part[t - off] : 0;
    __syncthreads();
    part[t] += v;
    __syncthreads();
  }
  int run = part[t] - s;  // exclusive prefix
  for (int j = 0; j < 64; ++j) {
    int c = count[base + j];
    offsets[base + j] = run;
    count[base + j] = run;  // becomes cursor for k_fill
    run += c;
  }
  if (t == 255) offsets[NA] = run;
}

__global__ void k_fill(const int* __restrict__ rad, const int* __restrict__ bon,
                       int* __restrict__ cursor, int* __restrict__ sorted) {
  int e = blockIdx.x * 256 + threadIdx.x;
  int d = edge_dst(e, rad, bon);
  int slot = atomicAdd(&cursor[d], 1);
  sorted[slot] = e;
}

// ---------------- per-edge record precompute ----------------
// record[idx] (48B, CSR slot order): {src|(isBond<<16), Y0,Y1,Y2}, {rb0..3}, {rb4..7}
__global__ void k_edge_pre(const float* __restrict__ pos,
                           const int* __restrict__ rad, const int* __restrict__ bon,
                           const int* __restrict__ sorted, float4* __restrict__ rec) {
  int idx = blockIdx.x * 256 + threadIdx.x;
  int e = sorted[idx];
  int src, dst, flag;
  if (e < ER) { src = rad[e]; dst = rad[ER + e]; flag = 0; }
  else        { src = bon[e - ER]; dst = bon[EB + e - ER]; flag = 1 << 16; }
  float dx = pos[src * 3] - pos[dst * 3];
  float dy = pos[src * 3 + 1] - pos[dst * 3 + 1];
  float dz = pos[src * 3 + 2] - pos[dst * 3 + 2];
  float dist = sqrtf(dx * dx + dy * dy + dz * dz + 1e-12f);
  float inv = 1.f / dist;
  float4* rp = rec + (size_t)idx * 3;
  rp[0] = make_float4(__int_as_float(src | flag), SQRT3 * dx * inv, SQRT3 * dy * inv, SQRT3 * dz * inv);
  float rb[8];
#pragma unroll
  for (int k = 0; k < 8; ++k) {
    float diff = (dist - (k + 1) * RB_STEP) * (1.f / RB_STEP);
    rb[k] = 1.12f * __expf(-diff * diff);
  }
  rp[1] = make_float4(rb[0], rb[1], rb[2], rb[3]);
  rp[2] = make_float4(rb[4], rb[5], rb[6], rb[7]);
}

// ---------------- embedding ----------------
__global__ void k_embed(const float* __restrict__ atom_tab, const int* __restrict__ types,
                        const float* __restrict__ ns0_w, const float* __restrict__ cnoise,
                        float* __restrict__ s_feat) {
  int tid = blockIdx.x * 256 + threadIdx.x;
  int n = tid >> 6, c = tid & 63;
  float cn = cnoise[0];
  s_feat[tid] = atom_tab[types[n] * 64 + c] * (1.f + cn * ns0_w[c]);
}

// ---------------- initial aggregation (wave per node, lane = channel) ----------------
__global__ __launch_bounds__(256, 4) void k_agg0(
    const float* __restrict__ bond_tab,
    const float* __restrict__ We0, const float* __restrict__ We1,
    const int* __restrict__ offsets, const float4* __restrict__ rec,
    const float* __restrict__ s_feat,
    float* __restrict__ a_s, float* __restrict__ a_v) {
  int lane = threadIdx.x & 63;
  int n = blockIdx.x * 4 + (threadIdx.x >> 6);
  int c = lane;
  float w0r[8], w1r[8];
  float w0b0 = 0, w0b1 = 0, w1b0 = 0, w1b1 = 0;
#pragma unroll
  for (int k = 0; k < 8; ++k) {
    w0r[k] = We0[(8 + k) * 64 + c];
    w1r[k] = We1[(8 + k) * 64 + c];
    float bt0 = bond_tab[k], bt1 = bond_tab[8 + k];
    float c0 = We0[k * 64 + c], c1 = We1[k * 64 + c];
    w0b0 += bt0 * c0; w0b1 += bt1 * c0;
    w1b0 += bt0 * c1; w1b1 += bt1 * c1;
  }
#pragma unroll
  for (int k = 0; k < 8; ++k) { KEEP(w0r[k]); KEEP(w1r[k]); }
  KEEP(w0b0); KEEP(w0b1); KEEP(w1b0); KEEP(w1b1);

  float acc = 0, a0 = 0, a1 = 0, a2 = 0;
  int beg = __builtin_amdgcn_readfirstlane(offsets[n]);
  int end = __builtin_amdgcn_readfirstlane(offsets[n + 1]);
  if (beg < end) {
    // software pipeline: cur record + cur gathers + next record pre-issued
    const float4* rp = rec + (size_t)beg * 3;
    float4 c0 = ntl4(rp), c1 = ntl4(rp + 1), c2 = ntl4(rp + 2);
    int src = __float_as_int(c0.x) & 0xFFFF;
    float sv = s_feat[src * 64 + c];
    int j1 = (beg + 1 < end) ? beg + 1 : beg;
    const float4* rp1 = rec + (size_t)j1 * 3;
    float4 n0 = ntl4(rp1), n1 = ntl4(rp1 + 1), n2 = ntl4(rp1 + 2);
    for (int idx = beg; idx < end; ++idx) {
      // prefetch: gathers for idx+1 (from n-record), record for idx+2
      int nsrc = __float_as_int(n0.x) & 0xFFFF;
      float nsv = s_feat[nsrc * 64 + c];
      int j2 = (idx + 2 < end) ? idx + 2 : end - 1;
      const float4* rpf = rec + (size_t)j2 * 3;
      float4 f0 = ntl4(rpf), f1 = ntl4(rpf + 1), f2 = ntl4(rpf + 2);
      // compute for idx
      bool isB = __float_as_int(c0.x) >= (1 << 16);
      float w0 = isB ? w0b1 : w0b0;
      float w1 = isB ? w1b1 : w1b0;
      w0 += c1.x * w0r[0] + c1.y * w0r[1] + c1.z * w0r[2] + c1.w * w0r[3]
          + c2.x * w0r[4] + c2.y * w0r[5] + c2.z * w0r[6] + c2.w * w0r[7];
      w1 += c1.x * w1r[0] + c1.y * w1r[1] + c1.z * w1r[2] + c1.w * w1r[3]
          + c2.x * w1r[4] + c2.y * w1r[5] + c2.z * w1r[6] + c2.w * w1r[7];
      acc += w0 * sv;
      float t = w1 * sv;
      a0 += t * c0.y; a1 += t * c0.z; a2 += t * c0.w;
      // rotate
      c0 = n0; c1 = n1; c2 = n2; n0 = f0; n1 = f1; n2 = f2; sv = nsv;
    }
  }
  a_s[n * 64 + c] = acc * INV_NORM;
  float* avp = a_v + (size_t)n * 192 + c * 3;
  avp[0] = a0 * INV_NORM; avp[1] = a1 * INV_NORM; avp[2] = a2 * INV_NORM;
}

// ---------------- initial projections (merged sh + vh) ----------------
__global__ void k_init(const float* __restrict__ a_s, const float* __restrict__ s_feat,
                       const float* __restrict__ Ws0, const float* __restrict__ Wself0,
                       const float* __restrict__ a_v, const float* __restrict__ Wv0,
                       float* __restrict__ sh, float* __restrict__ vh) {
  int b = blockIdx.x;
  if (b < NA * 64 / 256) {
    int tid = b * 256 + threadIdx.x;
    int n = tid >> 6, d = tid & 63;
    float acc = 0;
    const float* as = a_s + n * 64;
    const float* sp = s_feat + n * 64;
    for (int c = 0; c < 64; ++c)
      acc += as[c] * Ws0[c * 64 + d] + sp[c] * Wself0[c * 64 + d];
    sh[tid] = acc;
  } else {
    int tid = (b - NA * 64 / 256) * 256 + threadIdx.x;
    int n = tid >> 5, d = tid & 31;
    float a0 = 0, a1 = 0, a2 = 0;
    const float* av = a_v + (size_t)n * 192;
    for (int c = 0; c < 64; ++c) {
      float w = Wv0[c * 32 + d];
      a0 += av[c * 3] * w; a1 += av[c * 3 + 1] * w; a2 += av[c * 3 + 2] * w;
    }
    float* o = vh + (size_t)n * 128 + d * 4;  // padded [n][32][4]
    o[0] = a0; o[1] = a1; o[2] = a2;
  }
}

// ---------------- layer aggregation (wave per node) ----------------
__global__ __launch_bounds__(256, 4) void k_agg_layer(
    const float* __restrict__ cnoise, const float* __restrict__ bond_tab,
    const float* __restrict__ Wss, const float* __restrict__ Wvs,
    const float* __restrict__ Wsv, const float* __restrict__ Wvv,
    const float* __restrict__ Wvx, const float* __restrict__ nsw,
    const int* __restrict__ offsets, const float4* __restrict__ rec,
    const float* __restrict__ sh_in, const float4* __restrict__ vh_in,
    float* __restrict__ a_s, float* __restrict__ a_v) {
  int lane = threadIdx.x & 63;
  int n = blockIdx.x * 4 + (threadIdx.x >> 6);
  int c = lane;
  int vc = lane & 31;
  bool low = lane < 32;
  float cn = cnoise[0];

  float rss[8], rsv[8], rva[8], rvb[8];
  float bss0 = 0, bss1 = 0, bsv0 = 0, bsv1 = 0, bva0 = 0, bva1 = 0, bvb0 = 0, bvb1 = 0;
#pragma unroll
  for (int k = 0; k < 8; ++k) {
    float wss_lo = Wss[k * 64 + c], wss_hi = Wss[(8 + k) * 64 + c];
    float wsv_lo = Wsv[k * 64 + c], wsv_hi = Wsv[(8 + k) * 64 + c];
    float wa_lo = low ? Wvs[k * 32 + vc] : Wvx[k * 32 + vc];
    float wa_hi = low ? Wvs[(8 + k) * 32 + vc] : Wvx[(8 + k) * 32 + vc];
    float wb_lo = low ? Wvv[k * 32 + vc] : 0.f;
    float wb_hi = low ? Wvv[(8 + k) * 32 + vc] : 0.f;
    float bt0 = bond_tab[k], bt1 = bond_tab[8 + k];
    rss[k] = wss_hi; rsv[k] = wsv_hi; rva[k] = wa_hi; rvb[k] = wb_hi;
    bss0 += bt0 * wss_lo; bss1 += bt1 * wss_lo;
    bsv0 += bt0 * wsv_lo; bsv1 += bt1 * wsv_lo;
    bva0 += bt0 * wa_lo;  bva1 += bt1 * wa_lo;
    bvb0 += bt0 * wb_lo;  bvb1 += bt1 * wb_lo;
  }
#pragma unroll
  for (int k = 0; k < 8; ++k) { KEEP(rss[k]); KEEP(rsv[k]); KEEP(rva[k]); KEEP(rvb[k]); }
  KEEP(bss0); KEEP(bss1); KEEP(bsv0); KEEP(bsv1);
  KEEP(bva0); KEEP(bva1); KEEP(bvb0); KEEP(bvb1);

  float scale_s = 1.f + cn * nsw[c];
  float scale_v = 1.f + cn * nsw[64 + vc];

  float ms = 0;                    // sum w_ss*sh        (scale_s folded at store)
  float av0 = 0, av1 = 0, av2 = 0; // sum w_sv*sh*Y      (scale_s folded)
  float ms2 = 0;                   // low: sum w_vs*(v.Y) (scale_v folded)
  float b0 = 0, b1 = 0, b2 = 0;    // low: w_vv*v ; high: w_vx*cross(v,Y) (scale_v folded)
  int beg = __builtin_amdgcn_readfirstlane(offsets[n]);
  int end = __builtin_amdgcn_readfirstlane(offsets[n + 1]);
  if (beg < end) {
    const float4* rp = rec + (size_t)beg * 3;
    float4 c0 = ntl4(rp), c1 = ntl4(rp + 1), c2 = ntl4(rp + 2);
    int src = __float_as_int(c0.x) & 0xFFFF;
    float ss = sh_in[src * 64 + c];
    float4 v4 = vh_in[src * 32 + vc];
    int j1 = (beg + 1 < end) ? beg + 1 : beg;
    const float4* rp1 = rec + (size_t)j1 * 3;
    float4 n0 = ntl4(rp1), n1 = ntl4(rp1 + 1), n2 = ntl4(rp1 + 2);
    for (int idx = beg; idx < end; ++idx) {
      // prefetch stage: gathers for idx+1, record for idx+2
      int nsrc = __float_as_int(n0.x) & 0xFFFF;
      float nss = sh_in[nsrc * 64 + c];
      float4 nv4 = vh_in[nsrc * 32 + vc];
      int j2 = (idx + 2 < end) ? idx + 2 : end - 1;
      const float4* rpf = rec + (size_t)j2 * 3;
      float4 f0 = ntl4(rpf), f1 = ntl4(rpf + 1), f2 = ntl4(rpf + 2);
      // compute for idx
      bool isB = __float_as_int(c0.x) >= (1 << 16);
      float y0 = c0.y, y1 = c0.z, y2 = c0.w;
      float wS  = isB ? bss1 : bss0;
      float wSV = isB ? bsv1 : bsv0;
      float wA  = isB ? bva1 : bva0;
      float wB  = isB ? bvb1 : bvb0;
      wS  += c1.x * rss[0] + c1.y * rss[1] + c1.z * rss[2] + c1.w * rss[3]
           + c2.x * rss[4] + c2.y * rss[5] + c2.z * rss[6] + c2.w * rss[7];
      wSV += c1.x * rsv[0] + c1.y * rsv[1] + c1.z * rsv[2] + c1.w * rsv[3]
           + c2.x * rsv[4] + c2.y * rsv[5] + c2.z * rsv[6] + c2.w * rsv[7];
      wA  += c1.x * rva[0] + c1.y * rva[1] + c1.z * rva[2] + c1.w * rva[3]
           + c2.x * rva[4] + c2.y * rva[5] + c2.z * rva[6] + c2.w * rva[7];
      wB  += c1.x * rvb[0] + c1.y * rvb[1] + c1.z * rvb[2] + c1.w * rvb[3]
           + c2.x * rvb[4] + c2.y * rvb[5] + c2.z * rvb[6] + c2.w * rvb[7];
      float v0 = v4.x, v1 = v4.y, v2 = v4.z;
      ms += wS * ss;
      float t = wSV * ss;
      av0 += t * y0; av1 += t * y1; av2 += t * y2;
      float vdot = v0 * y0 + v1 * y1 + v2 * y2;
      ms2 += wA * vdot;  // garbage on high lanes, never written
      float cx = v1 * y2 - v2 * y1;
      float cy = v2 * y0 - v0 * y2;
      float cz = v0 * y1 - v1 * y0;
      float m0 = low ? v0 : cx;
      float m1 = low ? v1 : cy;
      float m2 = low ? v2 : cz;
      float wM = low ? wB : wA;
      b0 += wM * m0; b1 += wM * m1; b2 += wM * m2;
      // rotate
      c0 = n0; c1 = n1; c2 = n2; n0 = f0; n1 = f1; n2 = f2; ss = nss; v4 = nv4;
    }
  }
  float fs = scale_s * INV_NORM;
  float fv = scale_v * INV_NORM;
  a_s[n * 96 + c] = ms * fs;
  float* avn = a_v + (size_t)n * 384;
  avn[c * 3] = av0 * fs; avn[c * 3 + 1] = av1 * fs; avn[c * 3 + 2] = av2 * fs;
  if (low) {
    a_s[n * 96 + 64 + vc] = ms2 * fv;
    avn[(64 + vc) * 3] = b0 * fv;
    avn[(64 + vc) * 3 + 1] = b1 * fv;
    avn[(64 + vc) * 3 + 2] = b2 * fv;
  } else {
    avn[(96 + vc) * 3] = b0 * fv;
    avn[(96 + vc) * 3 + 1] = b1 * fv;
    avn[(96 + vc) * 3 + 2] = b2 * fv;
  }
}

// ---------------- mixing / self / skip (merged s + v) ----------------
__global__ void k_mix(const float* __restrict__ a_s, const float* __restrict__ sh_in,
                      const float* __restrict__ Wmix_s, const float* __restrict__ Wself_s,
                      const float* __restrict__ a_v, const float* __restrict__ vh_in,
                      const float* __restrict__ Wmix_v, const float* __restrict__ Wself_v,
                      const float* __restrict__ nsw, const float* __restrict__ skw,
                      const float* __restrict__ skb, const float* __restrict__ cnoise,
                      float* __restrict__ sh_out, float* __restrict__ vh_out) {
  int b = blockIdx.x;
  float cn = cnoise[0];
  if (b < NA * 64 / 256) {
    int tid = b * 256 + threadIdx.x;
    int n = tid >> 6, d = tid & 63;
    float acc = 0;
    const float* as = a_s + n * 96;
    for (int cc = 0; cc < 96; ++cc) acc += as[cc] * Wmix_s[cc * 64 + d];
    const float* sp = sh_in + n * 64;
    for (int cc = 0; cc < 64; ++cc) acc += sp[cc] * (1.f + cn * nsw[cc]) * Wself_s[cc * 64 + d];
    float g1 = sigmoidf_(skb[d] + cn * skw[d]);
    float g2 = sigmoidf_(skb[64 + d] + cn * skw[64 + d]);
    sh_out[tid] = g1 * sh_in[tid] + g2 * acc;
  } else {
    int tid = (b - NA * 64 / 256) * 256 + threadIdx.x;
    int n = tid >> 5, d = tid & 31;
    float a0 = 0, a1 = 0, a2 = 0;
    const float* av = a_v + (size_t)n * 384;
    for (int cc = 0; cc < 128; ++cc) {
      float w = Wmix_v[cc * 32 + d];
      a0 += av[cc * 3] * w; a1 += av[cc * 3 + 1] * w; a2 += av[cc * 3 + 2] * w;
    }
    const float* vp = vh_in + (size_t)n * 128;
    for (int cc = 0; cc < 32; ++cc) {
      float w = Wself_v[cc * 32 + d] * (1.f + cn * nsw[64 + cc]);
      a0 += vp[cc * 4] * w; a1 += vp[cc * 4 + 1] * w; a2 += vp[cc * 4 + 2] * w;
    }
    float g3 = sigmoidf_(skb[128 + d] + cn * skw[128 + d]);
    float g4 = sigmoidf_(skb[160 + d] + cn * skw[160 + d]);
    float* o = vh_out + (size_t)n * 128 + d * 4;
    const float* vi = vh_in + (size_t)n * 128 + d * 4;
    o[0] = g3 * vi[0] + g4 * a0;
    o[1] = g3 * vi[1] + g4 * a1;
    o[2] = g3 * vi[2] + g4 * a2;
  }
}

// ---------------- output ----------------
__global__ void k_out(const float* __restrict__ vh, const float* __restrict__ w_out,
                      const float* __restrict__ gain, float* __restrict__ out) {
  int tid = blockIdx.x * 256 + threadIdx.x;  // < NA*3
  int n = tid / 3, i = tid - n * 3;
  float acc = 0;
  for (int c = 0; c < 32; ++c) acc += vh[(size_t)n * 128 + c * 4 + i] * w_out[c];
  out[tid] = acc * gain[0];
}

extern "C" void kernel_launch(void* const* d_in, const int* in_sizes, int n_in,
                              void* d_out, int out_size, void* d_ws, size_t ws_size,
                              hipStream_t stream) {
  (void)in_sizes; (void)n_in; (void)out_size; (void)ws_size;
  const float* pos     = (const float*)d_in[0];
  const float* cn      = (const float*)d_in[1];
  const int*   types   = (const int*)d_in[2];
  const int*   rad     = (const int*)d_in[3];
  const int*   bon     = (const int*)d_in[4];
  const float* atom_tab= (const float*)d_in[5];
  const float* bond_tab= (const float*)d_in[6];
  const float* ns0_w   = (const float*)d_in[7];
  const float* We0     = (const float*)d_in[8];
  const float* We1     = (const float*)d_in[9];
  const float* Wself0  = (const float*)d_in[10];
  const float* Ws0     = (const float*)d_in[11];
  const float* Wv0     = (const float*)d_in[12];
  const float* ns_w    = (const float*)d_in[13];
  const float* We_ss   = (const float*)d_in[14];
  const float* We_vs   = (const float*)d_in[15];
  const float* We_sv   = (const float*)d_in[16];
  const float* We_vv   = (const float*)d_in[17];
  const float* We_vx   = (const float*)d_in[18];
  const float* Wmix_s  = (const float*)d_in[19];
  const float* Wmix_v  = (const float*)d_in[20];
  const float* Wself_s = (const float*)d_in[21];
  const float* Wself_v = (const float*)d_in[22];
  const float* skip_w  = (const float*)d_in[23];
  const float* skip_b  = (const float*)d_in[24];
  const float* w_out   = (const float*)d_in[25];
  const float* gain    = (const float*)d_in[26];

  char* ws = (char*)d_ws;
  size_t o = 0;
  auto alloc = [&](size_t bytes) -> void* {
    void* p = ws + o;
    o += (bytes + 255) & ~(size_t)255;
    return p;
  };
  float* s_feat = (float*)alloc((size_t)NA * 64 * 4);
  float* a_s    = (float*)alloc((size_t)NA * 96 * 4);
  float* a_v    = (float*)alloc((size_t)NA * 384 * 4);
  float* sh0    = (float*)alloc((size_t)NA * 64 * 4);
  float* sh1    = (float*)alloc((size_t)NA * 64 * 4);
  float* vh0    = (float*)alloc((size_t)NA * 128 * 4);  // padded [n][32][4]
  float* vh1    = (float*)alloc((size_t)NA * 128 * 4);
  int* count    = (int*)alloc((size_t)NA * 4);
  int* offsets  = (int*)alloc((size_t)(NA + 1) * 4);
  int* sorted   = (int*)alloc((size_t)ET * 4);
  float4* rec   = (float4*)alloc((size_t)ET * 48);
  float* shb[2] = {sh0, sh1};
  float* vhb[2] = {vh0, vh1};

  // CSR build
  k_zero<<<NA / 256, 256, 0, stream>>>(count);
  k_hist<<<ET / 256, 256, 0, stream>>>(rad, bon, count);
  k_scan<<<1, 256, 0, stream>>>(count, offsets);
  k_fill<<<ET / 256, 256, 0, stream>>>(rad, bon, count, sorted);
  k_edge_pre<<<ET / 256, 256, 0, stream>>>(pos, rad, bon, sorted, rec);

  k_embed<<<NA * 64 / 256, 256, 0, stream>>>(atom_tab, types, ns0_w, cn, s_feat);
  k_agg0<<<NA / 4, 256, 0, stream>>>(bond_tab, We0, We1, offsets, rec, s_feat, a_s, a_v);
  k_init<<<NA * 64 / 256 + NA * 32 / 256, 256, 0, stream>>>(
      a_s, s_feat, Ws0, Wself0, a_v, Wv0, shb[0], vhb[0]);

  for (int l = 0; l < 2; ++l) {
    int bin = l & 1, bout = 1 - bin;
    k_agg_layer<<<NA / 4, 256, 0, stream>>>(
        cn, bond_tab,
        We_ss + l * 16 * 64, We_vs + l * 16 * 32, We_sv + l * 16 * 64,
        We_vv + l * 16 * 32, We_vx + l * 16 * 32, ns_w + l * 96,
        offsets, rec, shb[bin], (const float4*)vhb[bin], a_s, a_v);
    k_mix<<<NA * 64 / 256 + NA * 32 / 256, 256, 0, stream>>>(
        a_s, shb[bin], Wmix_s + l * 96 * 64, Wself_s + l * 64 * 64,
        a_v, vhb[bin], Wmix_v + l * 128 * 32, Wself_v + l * 32 * 32,
        ns_w + l * 96, skip_w + l * 192, skip_b + l * 192, cn, shb[bout], vhb[bout]);
  }
  k_out<<<NA * 3 / 256, 256, 0, stream>>>(vhb[0], w_out, gain, (float*)d_out);
}